// Round 5
// baseline (305.008 us; speedup 1.0000x reference)
//
#include <hip/hip_runtime.h>
#include <hip/hip_bf16.h>
#include <math.h>

// out = LN2( gelu_erf( LN1(x) @ W^T + bW ) )
// x: [4,4096,2048] f32 -> M=16384 rows. W: [2048,2048] f32, C[m,e]=sum_d h[m,d]*W[e,d].
// GEMM: 256x256 tile, 64 K-slices of 32. LDS is FRAGMENT-MAJOR: within each 16-row
// region, byte l*16 holds lane l's MFMA frag chunk (row l&15, kchunk l>>4), so every
// ds_read_b128 is base + lane*16 (linear, conflict-free). The gather is done on the
// global_load_lds SOURCE address. 4 slice regions, stage lead = 3 phases, vmcnt(8).

#define D 2048
#define MROWS 16384
#define BMT 256
#define BNT 256
#define NSLICES 64

typedef __bf16 bf16x8 __attribute__((ext_vector_type(8)));
typedef float f32x4 __attribute__((ext_vector_type(4)));

#define GLP(p) ((const __attribute__((address_space(1))) void*)(p))
#define LDSP(p) ((__attribute__((address_space(3))) void*)(p))
#define S_VMCNT(n) asm volatile("s_waitcnt vmcnt(" #n ")" ::: "memory")
#define MEMFENCE() asm volatile("" ::: "memory")
#define BAR() __builtin_amdgcn_s_barrier()
#define SCHED_FENCE() __builtin_amdgcn_sched_barrier(0)

__device__ __forceinline__ float gelu_f(float v) {
  return 0.5f * v * (1.0f + erff(v * 0.70710678118654752f));
}

// ---------------- LN1: f32 row -> bf16 row ----------------
__global__ __launch_bounds__(256) void ln1_kernel(
    const float* __restrict__ x, const float* __restrict__ g,
    const float* __restrict__ b, __hip_bfloat16* __restrict__ out) {
  const int tid = threadIdx.x;
  const size_t row = blockIdx.x;
  const float4* xr = (const float4*)(x + row * D);
  float4 v0 = xr[2 * tid];
  float4 v1 = xr[2 * tid + 1];
  float s  = v0.x + v0.y + v0.z + v0.w + v1.x + v1.y + v1.z + v1.w;
  float ss = v0.x*v0.x + v0.y*v0.y + v0.z*v0.z + v0.w*v0.w
           + v1.x*v1.x + v1.y*v1.y + v1.z*v1.z + v1.w*v1.w;
#pragma unroll
  for (int off = 32; off > 0; off >>= 1) {
    s  += __shfl_down(s, off, 64);
    ss += __shfl_down(ss, off, 64);
  }
  __shared__ float red[8];
  const int w = tid >> 6;
  if ((tid & 63) == 0) { red[w] = s; red[w + 4] = ss; }
  __syncthreads();
  s  = red[0] + red[1] + red[2] + red[3];
  ss = red[4] + red[5] + red[6] + red[7];
  const float mu  = s * (1.0f / D);
  const float var = ss * (1.0f / D) - mu * mu;
  const float inv = rsqrtf(var + 1e-5f);
  const float4* gv = (const float4*)g;
  const float4* bv = (const float4*)b;
  float4 g0 = gv[2 * tid], g1 = gv[2 * tid + 1];
  float4 b0 = bv[2 * tid], b1 = bv[2 * tid + 1];
  alignas(16) __hip_bfloat16 h[8];
  h[0] = __float2bfloat16((v0.x - mu) * inv * g0.x + b0.x);
  h[1] = __float2bfloat16((v0.y - mu) * inv * g0.y + b0.y);
  h[2] = __float2bfloat16((v0.z - mu) * inv * g0.z + b0.z);
  h[3] = __float2bfloat16((v0.w - mu) * inv * g0.w + b0.w);
  h[4] = __float2bfloat16((v1.x - mu) * inv * g1.x + b1.x);
  h[5] = __float2bfloat16((v1.y - mu) * inv * g1.y + b1.y);
  h[6] = __float2bfloat16((v1.z - mu) * inv * g1.z + b1.z);
  h[7] = __float2bfloat16((v1.w - mu) * inv * g1.w + b1.w);
  *(uint4*)(out + row * D + (size_t)tid * 8) = *(const uint4*)h;
}

// ---------------- W: f32 -> bf16 ----------------
__global__ __launch_bounds__(256) void cvt_kernel(
    const float* __restrict__ W, __hip_bfloat16* __restrict__ Wb, int n8) {
  const int i = blockIdx.x * 256 + threadIdx.x;
  if (i >= n8) return;
  const float4* p = (const float4*)W + 2 * (size_t)i;
  float4 a = p[0], c = p[1];
  alignas(16) __hip_bfloat16 h[8] = {
      __float2bfloat16(a.x), __float2bfloat16(a.y),
      __float2bfloat16(a.z), __float2bfloat16(a.w),
      __float2bfloat16(c.x), __float2bfloat16(c.y),
      __float2bfloat16(c.z), __float2bfloat16(c.w)};
  *(uint4*)(Wb + (size_t)i * 8) = *(const uint4*)h;
}

// ---------------- GEMM: 256x256 tile, 8 waves (2M x 4N), fragment-major LDS ----------------
// Slice s (K cols s*32..+31): sA region (s&3)*16KB holds 16 regions of 1KB (16 rows each),
// region mi, byte l*16 = A[mi*16 + (l&15)][s*32 + (l>>4)*8 ..+7]. Same for sB (B rows = out cols).
// Staging: dest linear tid*16 (+8192); source gathers the matching (row, kchunk) per thread.
__global__ __launch_bounds__(512, 2) void gemm_kernel(
    const __hip_bfloat16* __restrict__ A,
    const __hip_bfloat16* __restrict__ Bw,
    const float* __restrict__ bias,
    float* __restrict__ C) {
  __shared__ __hip_bfloat16 sA[4 * 8192];  // 64KB: 4 slice regions x 16KB
  __shared__ __hip_bfloat16 sB[4 * 8192];  // 64KB
  const int tid = threadIdx.x;
  const int l = tid & 63;
  const int wid = tid >> 6;
  const int fr = l & 15;
  const int lk = l >> 4;
  const size_t m0 = (size_t)blockIdx.x * BMT;
  const int n0 = blockIdx.y * BNT;
  const int whm = wid >> 2;        // wave's A half (rows whm*128..+127)
  const int wn = (wid & 3) * 64;   // wave's col base in 0..255

  // staging source geometry: dest byte i*8192 + tid*16 holds row (i*128 + srow), col scol..+7
  const int srow = (tid >> 6) * 16 + (tid & 15);   // 0..127
  const int scol = ((tid >> 4) & 3) * 8;
  const int ldd = tid * 16;
  const __hip_bfloat16* const Ag = A + m0 * D + (size_t)srow * D + scol;
  const __hip_bfloat16* const Bg = Bw + (size_t)n0 * D + (size_t)srow * D + scol;

  auto stg = [&](int s) {                          // 4 global_load_lds per thread
    const int kb = s * 32;
    const int ro = (s & 3) << 14;
    __builtin_amdgcn_global_load_lds(GLP(Ag + kb), LDSP((char*)sA + ro + ldd), 16, 0, 0);
    __builtin_amdgcn_global_load_lds(GLP(Ag + (size_t)128 * D + kb), LDSP((char*)sA + ro + 8192 + ldd), 16, 0, 0);
    __builtin_amdgcn_global_load_lds(GLP(Bg + kb), LDSP((char*)sB + ro + ldd), 16, 0, 0);
    __builtin_amdgcn_global_load_lds(GLP(Bg + (size_t)128 * D + kb), LDSP((char*)sB + ro + 8192 + ldd), 16, 0, 0);
  };

  bf16x8 a[8], b[4];
  f32x4 acc[8][4] = {};
  const int abase = whm * 8192 + l * 16;           // A region base for this wave/lane
  const int bbase = (wid & 3) * 4096 + l * 16;     // B region base

  auto rd = [&](int s) {                           // 12 linear ds_read_b128
    const char* pa = (const char*)sA + ((s & 3) << 14) + abase;
    const char* pb = (const char*)sB + ((s & 3) << 14) + bbase;
#pragma unroll
    for (int mi = 0; mi < 8; ++mi) a[mi] = *(const bf16x8*)(pa + mi * 1024);
#pragma unroll
    for (int ni = 0; ni < 4; ++ni) b[ni] = *(const bf16x8*)(pb + ni * 1024);
  };
  auto mma = [&]() {
    __builtin_amdgcn_s_setprio(1);
#pragma unroll
    for (int mi = 0; mi < 8; ++mi)
#pragma unroll
      for (int ni = 0; ni < 4; ++ni)
        acc[mi][ni] = __builtin_amdgcn_mfma_f32_16x16x32_bf16(a[mi], b[ni], acc[mi][ni], 0, 0, 0);
    __builtin_amdgcn_s_setprio(0);
  };

  // prologue: slices 0,1,2 in flight (12 loads)
  stg(0); stg(1); stg(2);

  // steady state: at phase p top, outstanding = slices {p, p+1, p+2} (12 loads).
  // vmcnt(8) retires slice p (the one read this phase); stage(p+3) refills to 12.
  // Region reuse safety: stage(p+3) targets region (p-1)&3, whose ds_reads all completed
  // at phase p-1 (consumed by its MFMAs) before BAR(p); stage is issued after BAR(p).
  for (int p = 0; p < 61; ++p) {
    S_VMCNT(8);
    BAR(); MEMFENCE(); SCHED_FENCE();
    stg(p + 3);
    rd(p);
    mma();
  }
  S_VMCNT(8);  BAR(); MEMFENCE(); SCHED_FENCE(); rd(61); mma();
  S_VMCNT(4);  BAR(); MEMFENCE(); SCHED_FENCE(); rd(62); mma();
  S_VMCNT(0);  BAR(); MEMFENCE(); SCHED_FENCE(); rd(63); mma();

  // epilogue: bias + gelu, f32 stores (C/D: col=lane&15, row=(lane>>4)*4+reg)
  float bv[4];
#pragma unroll
  for (int ni = 0; ni < 4; ++ni) bv[ni] = bias[n0 + wn + ni * 16 + fr];
#pragma unroll
  for (int mi = 0; mi < 8; ++mi) {
    const size_t rbase = m0 + whm * 128 + mi * 16 + lk * 4;
#pragma unroll
    for (int rr = 0; rr < 4; ++rr) {
      float* crow = C + (rbase + rr) * D + n0 + wn + fr;
#pragma unroll
      for (int ni = 0; ni < 4; ++ni)
        crow[ni * 16] = gelu_f(acc[mi][ni][rr] + bv[ni]);
    }
  }
}

// ---------------- LN2: in-place f32 ----------------
__global__ __launch_bounds__(256) void ln2_kernel(
    float* __restrict__ C, const float* __restrict__ g, const float* __restrict__ b) {
  const int tid = threadIdx.x;
  const size_t row = blockIdx.x;
  float4* cr = (float4*)(C + row * D);
  float4 v0 = cr[2 * tid], v1 = cr[2 * tid + 1];
  float s  = v0.x + v0.y + v0.z + v0.w + v1.x + v1.y + v1.z + v1.w;
  float ss = v0.x*v0.x + v0.y*v0.y + v0.z*v0.z + v0.w*v0.w
           + v1.x*v1.x + v1.y*v1.y + v1.z*v1.z + v1.w*v1.w;
#pragma unroll
  for (int off = 32; off > 0; off >>= 1) {
    s  += __shfl_down(s, off, 64);
    ss += __shfl_down(ss, off, 64);
  }
  __shared__ float red[8];
  const int w = tid >> 6;
  if ((tid & 63) == 0) { red[w] = s; red[w + 4] = ss; }
  __syncthreads();
  s  = red[0] + red[1] + red[2] + red[3];
  ss = red[4] + red[5] + red[6] + red[7];
  const float mu  = s * (1.0f / D);
  const float var = ss * (1.0f / D) - mu * mu;
  const float inv = rsqrtf(var + 1e-5f);
  const float4* gv = (const float4*)g;
  const float4* bv = (const float4*)b;
  float4 g0 = gv[2 * tid], g1 = gv[2 * tid + 1];
  float4 b0 = bv[2 * tid], b1 = bv[2 * tid + 1];
  float4 o0, o1;
  o0.x = (v0.x - mu) * inv * g0.x + b0.x;
  o0.y = (v0.y - mu) * inv * g0.y + b0.y;
  o0.z = (v0.z - mu) * inv * g0.z + b0.z;
  o0.w = (v0.w - mu) * inv * g0.w + b0.w;
  o1.x = (v1.x - mu) * inv * g1.x + b1.x;
  o1.y = (v1.y - mu) * inv * g1.y + b1.y;
  o1.z = (v1.z - mu) * inv * g1.z + b1.z;
  o1.w = (v1.w - mu) * inv * g1.w + b1.w;
  cr[2 * tid] = o0;
  cr[2 * tid + 1] = o1;
}

extern "C" void kernel_launch(void* const* d_in, const int* in_sizes, int n_in,
                              void* d_out, int out_size, void* d_ws, size_t ws_size,
                              hipStream_t stream) {
  const float* x  = (const float*)d_in[0];
  const float* W  = (const float*)d_in[1];
  const float* bW = (const float*)d_in[2];
  const float* g1 = (const float*)d_in[3];
  const float* b1 = (const float*)d_in[4];
  const float* g2 = (const float*)d_in[5];
  const float* b2 = (const float*)d_in[6];
  float* out = (float*)d_out;

  __hip_bfloat16* Abf = (__hip_bfloat16*)d_ws;            // 64MB
  __hip_bfloat16* Wbf = Abf + (size_t)MROWS * D;          // +8MB

  ln1_kernel<<<MROWS, 256, 0, stream>>>(x, g1, b1, Abf);
  cvt_kernel<<<(D * D / 8) / 256, 256, 0, stream>>>(W, Wbf, D * D / 8);
  dim3 grid(MROWS / BMT, D / BNT);
  gemm_kernel<<<grid, 512, 0, stream>>>(Abf, Wbf, bW, out);
  ln2_kernel<<<MROWS, 256, 0, stream>>>(out, g2, b2);
}

// Round 6
// 258.261 us; speedup vs baseline: 1.1810x; 1.1810x over previous
//
#include <hip/hip_runtime.h>
#include <hip/hip_bf16.h>
#include <math.h>

// out = LN2( gelu_erf( LN1(x) @ W^T + bW ) )
// x: [4,4096,2048] f32 -> M=16384 rows. W: [2048,2048] f32, C[m,e]=sum_d h[m,d]*W[e,d].
// GEMM: 256x256 tile, 64 K-slices of 32, ring of 4 LDS slice-regions (fragment-major,
// conflict-free). m201-style fine phases: per slice 2 phases of
// {ds_reads ; 2 global_load_lds ; BAR ; setprio1 16xMFMA setprio0 ; BAR}, counted
// vmcnt(8) once per slice (never 0 until tail).

#define D 2048
#define MROWS 16384
#define BMT 256
#define BNT 256
#define NS 64

typedef __bf16 bf16x8 __attribute__((ext_vector_type(8)));
typedef float f32x4 __attribute__((ext_vector_type(4)));

#define GLP(p) ((const __attribute__((address_space(1))) void*)(p))
#define LDSP(p) ((__attribute__((address_space(3))) void*)(p))
#define S_VMCNT(n) asm volatile("s_waitcnt vmcnt(" #n ")" ::: "memory")
#define MEMFENCE() asm volatile("" ::: "memory")
#define BAR() __builtin_amdgcn_s_barrier()
#define SCHED_FENCE() __builtin_amdgcn_sched_barrier(0)

__device__ __forceinline__ float gelu_f(float v) {
  return 0.5f * v * (1.0f + erff(v * 0.70710678118654752f));
}

// ---------------- LN1: f32 row -> bf16 row ----------------
__global__ __launch_bounds__(256) void ln1_kernel(
    const float* __restrict__ x, const float* __restrict__ g,
    const float* __restrict__ b, __hip_bfloat16* __restrict__ out) {
  const int tid = threadIdx.x;
  const size_t row = blockIdx.x;
  const float4* xr = (const float4*)(x + row * D);
  float4 v0 = xr[2 * tid];
  float4 v1 = xr[2 * tid + 1];
  float s  = v0.x + v0.y + v0.z + v0.w + v1.x + v1.y + v1.z + v1.w;
  float ss = v0.x*v0.x + v0.y*v0.y + v0.z*v0.z + v0.w*v0.w
           + v1.x*v1.x + v1.y*v1.y + v1.z*v1.z + v1.w*v1.w;
#pragma unroll
  for (int off = 32; off > 0; off >>= 1) {
    s  += __shfl_down(s, off, 64);
    ss += __shfl_down(ss, off, 64);
  }
  __shared__ float red[8];
  const int w = tid >> 6;
  if ((tid & 63) == 0) { red[w] = s; red[w + 4] = ss; }
  __syncthreads();
  s  = red[0] + red[1] + red[2] + red[3];
  ss = red[4] + red[5] + red[6] + red[7];
  const float mu  = s * (1.0f / D);
  const float var = ss * (1.0f / D) - mu * mu;
  const float inv = rsqrtf(var + 1e-5f);
  const float4* gv = (const float4*)g;
  const float4* bv = (const float4*)b;
  float4 g0 = gv[2 * tid], g1 = gv[2 * tid + 1];
  float4 b0 = bv[2 * tid], b1 = bv[2 * tid + 1];
  alignas(16) __hip_bfloat16 h[8];
  h[0] = __float2bfloat16((v0.x - mu) * inv * g0.x + b0.x);
  h[1] = __float2bfloat16((v0.y - mu) * inv * g0.y + b0.y);
  h[2] = __float2bfloat16((v0.z - mu) * inv * g0.z + b0.z);
  h[3] = __float2bfloat16((v0.w - mu) * inv * g0.w + b0.w);
  h[4] = __float2bfloat16((v1.x - mu) * inv * g1.x + b1.x);
  h[5] = __float2bfloat16((v1.y - mu) * inv * g1.y + b1.y);
  h[6] = __float2bfloat16((v1.z - mu) * inv * g1.z + b1.z);
  h[7] = __float2bfloat16((v1.w - mu) * inv * g1.w + b1.w);
  *(uint4*)(out + row * D + (size_t)tid * 8) = *(const uint4*)h;
}

// ---------------- W: f32 -> bf16 ----------------
__global__ __launch_bounds__(256) void cvt_kernel(
    const float* __restrict__ W, __hip_bfloat16* __restrict__ Wb, int n8) {
  const int i = blockIdx.x * 256 + threadIdx.x;
  if (i >= n8) return;
  const float4* p = (const float4*)W + 2 * (size_t)i;
  float4 a = p[0], c = p[1];
  alignas(16) __hip_bfloat16 h[8] = {
      __float2bfloat16(a.x), __float2bfloat16(a.y),
      __float2bfloat16(a.z), __float2bfloat16(a.w),
      __float2bfloat16(c.x), __float2bfloat16(c.y),
      __float2bfloat16(c.z), __float2bfloat16(c.w)};
  *(uint4*)(Wb + (size_t)i * 8) = *(const uint4*)h;
}

// ---------------- GEMM: 256x256 tile, 8 waves (2M x 4N), fragment-major LDS, 8-phase ----------------
// Slice s region (s&3)*16KB per operand: 16 frag-regions x 1KB; byte l*16 of frag fi holds
// M[fi*16 + (l&15)][s*32 + (l>>4)*8 ..+7]  => every ds_read_b128 is base + lane*16 (linear).
__global__ __launch_bounds__(512, 2) void gemm_kernel(
    const __hip_bfloat16* __restrict__ A,
    const __hip_bfloat16* __restrict__ Bw,
    const float* __restrict__ bias,
    float* __restrict__ C) {
  __shared__ __hip_bfloat16 sA[4 * 8192];  // 64KB: ring of 4 slice regions
  __shared__ __hip_bfloat16 sB[4 * 8192];  // 64KB
  const int tid = threadIdx.x;
  const int l = tid & 63;
  const int wid = tid >> 6;
  const int fr = l & 15;
  const int lk = l >> 4;
  const size_t m0 = (size_t)blockIdx.x * BMT;
  const int n0 = blockIdx.y * BNT;
  const int whm = wid >> 2;        // wave's A half (rows whm*128..+127)
  const int wn = (wid & 3) * 64;   // wave's col base in 0..255

  // staging source geometry (per thread): dest byte h*8192 + tid*16 of a region holds
  // row (h*128 + srow), cols scol..+7 of the slice.
  const int srow = ((tid >> 6) << 4) + (tid & 15);   // 0..127
  const int scol = ((tid >> 4) & 3) * 8;
  const int ldd = tid * 16;
  const __hip_bfloat16* const Ag = A + m0 * D + (size_t)srow * D + scol;
  const __hip_bfloat16* const Bg = Bw + (size_t)n0 * D + (size_t)srow * D + scol;

  auto stgA = [&](int s) {   // 2 global_load_lds
    const int ro = (s & 3) << 14;
    __builtin_amdgcn_global_load_lds(GLP(Ag + s * 32), LDSP((char*)sA + ro + ldd), 16, 0, 0);
    __builtin_amdgcn_global_load_lds(GLP(Ag + (size_t)128 * D + s * 32), LDSP((char*)sA + ro + 8192 + ldd), 16, 0, 0);
  };
  auto stgB = [&](int s) {   // 2 global_load_lds
    const int ro = (s & 3) << 14;
    __builtin_amdgcn_global_load_lds(GLP(Bg + s * 32), LDSP((char*)sB + ro + ldd), 16, 0, 0);
    __builtin_amdgcn_global_load_lds(GLP(Bg + (size_t)128 * D + s * 32), LDSP((char*)sB + ro + 8192 + ldd), 16, 0, 0);
  };

  bf16x8 a[8], b[4];
  f32x4 acc[8][4] = {};
  const int abase = whm * 8192 + l * 16;           // wave's A frag base within region
  const int bbase = (wid & 3) * 4096 + l * 16;     // wave's B frag base

  auto rdA8 = [&](int s) {                         // 8 linear ds_read_b128
    const char* pa = (const char*)sA + ((s & 3) << 14) + abase;
#pragma unroll
    for (int mi = 0; mi < 8; ++mi) a[mi] = *(const bf16x8*)(pa + mi * 1024);
  };
  auto rdB2 = [&](int s, int half) {               // 2 linear ds_read_b128
    const char* pb = (const char*)sB + ((s & 3) << 14) + bbase;
    b[half * 2]     = *(const bf16x8*)(pb + (half * 2) * 1024);
    b[half * 2 + 1] = *(const bf16x8*)(pb + (half * 2 + 1) * 1024);
  };
  auto mma16 = [&](int half) {                     // 16 MFMA: all mi x {ni = half*2, half*2+1}
    __builtin_amdgcn_s_setprio(1);
#pragma unroll
    for (int mi = 0; mi < 8; ++mi)
#pragma unroll
      for (int jb = 0; jb < 2; ++jb) {
        const int ni = half * 2 + jb;
        acc[mi][ni] = __builtin_amdgcn_mfma_f32_16x16x32_bf16(a[mi], b[ni], acc[mi][ni], 0, 0, 0);
      }
    __builtin_amdgcn_s_setprio(0);
  };

  // prologue: slices 0,1,2 staged (12 loads); retire slice 0 for all waves.
  stgA(0); stgB(0); stgA(1); stgB(1); stgA(2); stgB(2);
  S_VMCNT(8);
  BAR(); MEMFENCE(); SCHED_FENCE();

  for (int s = 0; s < NS; ++s) {
    // ---- phase 0: A frags + B half 0 ; stage A of slice s+3 ----
    rdA8(s); rdB2(s, 0);
    if (s < 61) stgA(s + 3);
    BAR();
    mma16(0);
    BAR();
    // ---- phase 1: B half 1 ; stage B of slice s+3 ----
    rdB2(s, 1);
    if (s < 61) stgB(s + 3);
    BAR();
    mma16(1);
    // ---- slice boundary: retire slice s+1 (counted; 0 only at tail) ----
    if (s < 61) { S_VMCNT(8); }
    else if (s == 61) { S_VMCNT(4); }
    else if (s == 62) { S_VMCNT(0); }
    BAR(); MEMFENCE(); SCHED_FENCE();
  }

  // epilogue: bias + gelu, f32 stores (C/D: col=lane&15, row=(lane>>4)*4+reg)
  float bv[4];
#pragma unroll
  for (int ni = 0; ni < 4; ++ni) bv[ni] = bias[n0 + wn + ni * 16 + fr];
#pragma unroll
  for (int mi = 0; mi < 8; ++mi) {
    const size_t rbase = m0 + whm * 128 + mi * 16 + lk * 4;
#pragma unroll
    for (int rr = 0; rr < 4; ++rr) {
      float* crow = C + (rbase + rr) * D + n0 + wn + fr;
#pragma unroll
      for (int ni = 0; ni < 4; ++ni)
        crow[ni * 16] = gelu_f(acc[mi][ni][rr] + bv[ni]);
    }
  }
}

// ---------------- LN2: in-place f32 ----------------
__global__ __launch_bounds__(256) void ln2_kernel(
    float* __restrict__ C, const float* __restrict__ g, const float* __restrict__ b) {
  const int tid = threadIdx.x;
  const size_t row = blockIdx.x;
  float4* cr = (float4*)(C + row * D);
  float4 v0 = cr[2 * tid], v1 = cr[2 * tid + 1];
  float s  = v0.x + v0.y + v0.z + v0.w + v1.x + v1.y + v1.z + v1.w;
  float ss = v0.x*v0.x + v0.y*v0.y + v0.z*v0.z + v0.w*v0.w
           + v1.x*v1.x + v1.y*v1.y + v1.z*v1.z + v1.w*v1.w;
#pragma unroll
  for (int off = 32; off > 0; off >>= 1) {
    s  += __shfl_down(s, off, 64);
    ss += __shfl_down(ss, off, 64);
  }
  __shared__ float red[8];
  const int w = tid >> 6;
  if ((tid & 63) == 0) { red[w] = s; red[w + 4] = ss; }
  __syncthreads();
  s  = red[0] + red[1] + red[2] + red[3];
  ss = red[4] + red[5] + red[6] + red[7];
  const float mu  = s * (1.0f / D);
  const float var = ss * (1.0f / D) - mu * mu;
  const float inv = rsqrtf(var + 1e-5f);
  const float4* gv = (const float4*)g;
  const float4* bv = (const float4*)b;
  float4 g0 = gv[2 * tid], g1 = gv[2 * tid + 1];
  float4 b0 = bv[2 * tid], b1 = bv[2 * tid + 1];
  float4 o0, o1;
  o0.x = (v0.x - mu) * inv * g0.x + b0.x;
  o0.y = (v0.y - mu) * inv * g0.y + b0.y;
  o0.z = (v0.z - mu) * inv * g0.z + b0.z;
  o0.w = (v0.w - mu) * inv * g0.w + b0.w;
  o1.x = (v1.x - mu) * inv * g1.x + b1.x;
  o1.y = (v1.y - mu) * inv * g1.y + b1.y;
  o1.z = (v1.z - mu) * inv * g1.z + b1.z;
  o1.w = (v1.w - mu) * inv * g1.w + b1.w;
  cr[2 * tid] = o0;
  cr[2 * tid + 1] = o1;
}

extern "C" void kernel_launch(void* const* d_in, const int* in_sizes, int n_in,
                              void* d_out, int out_size, void* d_ws, size_t ws_size,
                              hipStream_t stream) {
  const float* x  = (const float*)d_in[0];
  const float* W  = (const float*)d_in[1];
  const float* bW = (const float*)d_in[2];
  const float* g1 = (const float*)d_in[3];
  const float* b1 = (const float*)d_in[4];
  const float* g2 = (const float*)d_in[5];
  const float* b2 = (const float*)d_in[6];
  float* out = (float*)d_out;

  __hip_bfloat16* Abf = (__hip_bfloat16*)d_ws;            // 64MB
  __hip_bfloat16* Wbf = Abf + (size_t)MROWS * D;          // +8MB

  ln1_kernel<<<MROWS, 256, 0, stream>>>(x, g1, b1, Abf);
  cvt_kernel<<<(D * D / 8) / 256, 256, 0, stream>>>(W, Wbf, D * D / 8);
  dim3 grid(MROWS / BMT, D / BNT);
  gemm_kernel<<<grid, 512, 0, stream>>>(Abf, Wbf, bW, out);
  ln2_kernel<<<MROWS, 256, 0, stream>>>(out, g2, b2);
}

// Round 7
// 248.740 us; speedup vs baseline: 1.2262x; 1.0383x over previous
//
#include <hip/hip_runtime.h>
#include <hip/hip_bf16.h>
#include <math.h>

// out = LN2( gelu_erf( LN1(x) @ W^T + bW ) )
// x: [4,4096,2048] f32 -> M=16384 rows. W: [2048,2048] f32, C[m,e]=sum_d h[m,d]*W[e,d].
// GEMM: 256x256 tile, 64 K-slices of 32, ring of 4 fragment-major LDS slice regions
// (conflict-free, proven R5/R6). R7: one-slice REGISTER LOOKAHEAD — body(s) reads
// slice s+1 frags into the alternate reg set while MFMA consumes slice s, so each
// wave's LDS reads overlap its own MFMA. One barrier + one counted vmcnt per slice.

#define D 2048
#define MROWS 16384
#define BMT 256
#define BNT 256
#define NS 64

typedef __bf16 bf16x8 __attribute__((ext_vector_type(8)));
typedef float f32x4 __attribute__((ext_vector_type(4)));

#define GLP(p) ((const __attribute__((address_space(1))) void*)(p))
#define LDSP(p) ((__attribute__((address_space(3))) void*)(p))
#define S_VMCNT(n) asm volatile("s_waitcnt vmcnt(" #n ")" ::: "memory")
#define MEMFENCE() asm volatile("" ::: "memory")
#define BAR() __builtin_amdgcn_s_barrier()
#define SCHED_FENCE() __builtin_amdgcn_sched_barrier(0)

__device__ __forceinline__ float gelu_f(float v) {
  return 0.5f * v * (1.0f + erff(v * 0.70710678118654752f));
}

// ---------------- LN1: f32 row -> bf16 row ----------------
__global__ __launch_bounds__(256) void ln1_kernel(
    const float* __restrict__ x, const float* __restrict__ g,
    const float* __restrict__ b, __hip_bfloat16* __restrict__ out) {
  const int tid = threadIdx.x;
  const size_t row = blockIdx.x;
  const float4* xr = (const float4*)(x + row * D);
  float4 v0 = xr[2 * tid];
  float4 v1 = xr[2 * tid + 1];
  float s  = v0.x + v0.y + v0.z + v0.w + v1.x + v1.y + v1.z + v1.w;
  float ss = v0.x*v0.x + v0.y*v0.y + v0.z*v0.z + v0.w*v0.w
           + v1.x*v1.x + v1.y*v1.y + v1.z*v1.z + v1.w*v1.w;
#pragma unroll
  for (int off = 32; off > 0; off >>= 1) {
    s  += __shfl_down(s, off, 64);
    ss += __shfl_down(ss, off, 64);
  }
  __shared__ float red[8];
  const int w = tid >> 6;
  if ((tid & 63) == 0) { red[w] = s; red[w + 4] = ss; }
  __syncthreads();
  s  = red[0] + red[1] + red[2] + red[3];
  ss = red[4] + red[5] + red[6] + red[7];
  const float mu  = s * (1.0f / D);
  const float var = ss * (1.0f / D) - mu * mu;
  const float inv = rsqrtf(var + 1e-5f);
  const float4* gv = (const float4*)g;
  const float4* bv = (const float4*)b;
  float4 g0 = gv[2 * tid], g1 = gv[2 * tid + 1];
  float4 b0 = bv[2 * tid], b1 = bv[2 * tid + 1];
  alignas(16) __hip_bfloat16 h[8];
  h[0] = __float2bfloat16((v0.x - mu) * inv * g0.x + b0.x);
  h[1] = __float2bfloat16((v0.y - mu) * inv * g0.y + b0.y);
  h[2] = __float2bfloat16((v0.z - mu) * inv * g0.z + b0.z);
  h[3] = __float2bfloat16((v0.w - mu) * inv * g0.w + b0.w);
  h[4] = __float2bfloat16((v1.x - mu) * inv * g1.x + b1.x);
  h[5] = __float2bfloat16((v1.y - mu) * inv * g1.y + b1.y);
  h[6] = __float2bfloat16((v1.z - mu) * inv * g1.z + b1.z);
  h[7] = __float2bfloat16((v1.w - mu) * inv * g1.w + b1.w);
  *(uint4*)(out + row * D + (size_t)tid * 8) = *(const uint4*)h;
}

// ---------------- W: f32 -> bf16 ----------------
__global__ __launch_bounds__(256) void cvt_kernel(
    const float* __restrict__ W, __hip_bfloat16* __restrict__ Wb, int n8) {
  const int i = blockIdx.x * 256 + threadIdx.x;
  if (i >= n8) return;
  const float4* p = (const float4*)W + 2 * (size_t)i;
  float4 a = p[0], c = p[1];
  alignas(16) __hip_bfloat16 h[8] = {
      __float2bfloat16(a.x), __float2bfloat16(a.y),
      __float2bfloat16(a.z), __float2bfloat16(a.w),
      __float2bfloat16(c.x), __float2bfloat16(c.y),
      __float2bfloat16(c.z), __float2bfloat16(c.w)};
  *(uint4*)(Wb + (size_t)i * 8) = *(const uint4*)h;
}

// ---------------- GEMM: 256x256, 8 waves (2M x 4N), fragment-major LDS, reg lookahead ----------------
// Slice s region (s&3)*16KB per operand: 16 frag-blocks x 1KB; byte l*16 of block fi holds
// M[fi*16 + (l&15)][s*32 + (l>>4)*8 ..+7] => every ds_read_b128 is base + lane*16 (linear).
__global__ __launch_bounds__(512, 2) void gemm_kernel(
    const __hip_bfloat16* __restrict__ A,
    const __hip_bfloat16* __restrict__ Bw,
    const float* __restrict__ bias,
    float* __restrict__ C) {
  __shared__ __hip_bfloat16 sA[4 * 8192];  // 64KB: ring of 4 slice regions
  __shared__ __hip_bfloat16 sB[4 * 8192];  // 64KB
  const int tid = threadIdx.x;
  const int l = tid & 63;
  const int wid = tid >> 6;
  const int fr = l & 15;
  const int lk = l >> 4;
  const size_t m0 = (size_t)blockIdx.x * BMT;
  const int n0 = blockIdx.y * BNT;
  const int whm = wid >> 2;        // wave's A half (rows whm*128..+127)
  const int wn = (wid & 3) * 64;   // wave's col base in 0..255

  // staging source geometry: dest byte h*8192 + tid*16 of a region holds
  // row (h*128 + srow), cols scol..+7 of the slice.
  const int srow = ((tid >> 6) << 4) + (tid & 15);   // 0..127
  const int scol = ((tid >> 4) & 3) * 8;
  const int ldd = tid * 16;
  const __hip_bfloat16* const Ag = A + m0 * D + (size_t)srow * D + scol;
  const __hip_bfloat16* const Bg = Bw + (size_t)n0 * D + (size_t)srow * D + scol;

  auto stgA = [&](int s) {   // 2 global_load_lds
    const int ro = (s & 3) << 14;
    __builtin_amdgcn_global_load_lds(GLP(Ag + s * 32), LDSP((char*)sA + ro + ldd), 16, 0, 0);
    __builtin_amdgcn_global_load_lds(GLP(Ag + (size_t)128 * D + s * 32), LDSP((char*)sA + ro + 8192 + ldd), 16, 0, 0);
  };
  auto stgB = [&](int s) {   // 2 global_load_lds
    const int ro = (s & 3) << 14;
    __builtin_amdgcn_global_load_lds(GLP(Bg + s * 32), LDSP((char*)sB + ro + ldd), 16, 0, 0);
    __builtin_amdgcn_global_load_lds(GLP(Bg + (size_t)128 * D + s * 32), LDSP((char*)sB + ro + 8192 + ldd), 16, 0, 0);
  };

  const int abase = whm * 8192 + l * 16;           // wave's A frag base within region
  const int bbase = (wid & 3) * 4096 + l * 16;     // wave's B frag base

  bf16x8 aE[8], bE[4], aO[8], bO[4];               // double-buffered frag regs
  f32x4 acc[8][4] = {};

  auto rdA = [&](int s, bf16x8* ar) {              // 8 linear ds_read_b128
    const char* pa = (const char*)sA + ((s & 3) << 14) + abase;
#pragma unroll
    for (int mi = 0; mi < 8; ++mi) ar[mi] = *(const bf16x8*)(pa + mi * 1024);
  };
  auto rdB = [&](int s, bf16x8* br) {              // 4 linear ds_read_b128
    const char* pb = (const char*)sB + ((s & 3) << 14) + bbase;
#pragma unroll
    for (int ni = 0; ni < 4; ++ni) br[ni] = *(const bf16x8*)(pb + ni * 1024);
  };
  auto mma32 = [&](const bf16x8* ar, const bf16x8* br) {
    __builtin_amdgcn_s_setprio(1);
#pragma unroll
    for (int mi = 0; mi < 8; ++mi)
#pragma unroll
      for (int ni = 0; ni < 4; ++ni)
        acc[mi][ni] = __builtin_amdgcn_mfma_f32_16x16x32_bf16(ar[mi], br[ni], acc[mi][ni], 0, 0, 0);
    __builtin_amdgcn_s_setprio(0);
  };

  // prologue: stage slices 0,1,2 (12 loads); retire stage(0) for all waves; read slice 0.
  stgA(0); stgB(0); stgA(1); stgB(1); stgA(2); stgB(2);
  S_VMCNT(8);
  BAR(); MEMFENCE(); SCHED_FENCE();
  rdA(0, aE); rdB(0, bE);
  S_VMCNT(4);                          // retire stage(1); outstanding = stage(2) [4]
  BAR(); MEMFENCE(); SCHED_FENCE();

  // steady: body(s): read s+1 into nxt regs (stage(s+1) retired at previous boundary),
  // stage s+3, MFMA slice s from cur regs; boundary vmcnt(4) retires stage(s+2).
  for (int sp = 0; sp < 30; ++sp) {
    const int s0 = 2 * sp;
    rdA(s0 + 1, aO); rdB(s0 + 1, bO);
    stgA(s0 + 3); stgB(s0 + 3);
    mma32(aE, bE);
    S_VMCNT(4);
    BAR(); MEMFENCE(); SCHED_FENCE();
    rdA(s0 + 2, aE); rdB(s0 + 2, bE);
    stgA(s0 + 4); stgB(s0 + 4);
    mma32(aO, bO);
    S_VMCNT(4);
    BAR(); MEMFENCE(); SCHED_FENCE();
  }
  // s=60
  rdA(61, aO); rdB(61, bO);
  stgA(63); stgB(63);
  mma32(aE, bE);
  S_VMCNT(4);
  BAR(); MEMFENCE(); SCHED_FENCE();
  // s=61
  rdA(62, aE); rdB(62, bE);
  mma32(aO, bO);
  S_VMCNT(0);
  BAR(); MEMFENCE(); SCHED_FENCE();
  // s=62
  rdA(63, aO); rdB(63, bO);
  mma32(aE, bE);
  BAR(); MEMFENCE(); SCHED_FENCE();
  // s=63
  mma32(aO, bO);

  // epilogue: bias + gelu, f32 stores (C/D: col=lane&15, row=(lane>>4)*4+reg)
  float bv[4];
#pragma unroll
  for (int ni = 0; ni < 4; ++ni) bv[ni] = bias[n0 + wn + ni * 16 + fr];
#pragma unroll
  for (int mi = 0; mi < 8; ++mi) {
    const size_t rbase = m0 + whm * 128 + mi * 16 + lk * 4;
#pragma unroll
    for (int rr = 0; rr < 4; ++rr) {
      float* crow = C + (rbase + rr) * D + n0 + wn + fr;
#pragma unroll
      for (int ni = 0; ni < 4; ++ni)
        crow[ni * 16] = gelu_f(acc[mi][ni][rr] + bv[ni]);
    }
  }
}

// ---------------- LN2: in-place f32 ----------------
__global__ __launch_bounds__(256) void ln2_kernel(
    float* __restrict__ C, const float* __restrict__ g, const float* __restrict__ b) {
  const int tid = threadIdx.x;
  const size_t row = blockIdx.x;
  float4* cr = (float4*)(C + row * D);
  float4 v0 = cr[2 * tid], v1 = cr[2 * tid + 1];
  float s  = v0.x + v0.y + v0.z + v0.w + v1.x + v1.y + v1.z + v1.w;
  float ss = v0.x*v0.x + v0.y*v0.y + v0.z*v0.z + v0.w*v0.w
           + v1.x*v1.x + v1.y*v1.y + v1.z*v1.z + v1.w*v1.w;
#pragma unroll
  for (int off = 32; off > 0; off >>= 1) {
    s  += __shfl_down(s, off, 64);
    ss += __shfl_down(ss, off, 64);
  }
  __shared__ float red[8];
  const int w = tid >> 6;
  if ((tid & 63) == 0) { red[w] = s; red[w + 4] = ss; }
  __syncthreads();
  s  = red[0] + red[1] + red[2] + red[3];
  ss = red[4] + red[5] + red[6] + red[7];
  const float mu  = s * (1.0f / D);
  const float var = ss * (1.0f / D) - mu * mu;
  const float inv = rsqrtf(var + 1e-5f);
  const float4* gv = (const float4*)g;
  const float4* bv = (const float4*)b;
  float4 g0 = gv[2 * tid], g1 = gv[2 * tid + 1];
  float4 b0 = bv[2 * tid], b1 = bv[2 * tid + 1];
  float4 o0, o1;
  o0.x = (v0.x - mu) * inv * g0.x + b0.x;
  o0.y = (v0.y - mu) * inv * g0.y + b0.y;
  o0.z = (v0.z - mu) * inv * g0.z + b0.z;
  o0.w = (v0.w - mu) * inv * g0.w + b0.w;
  o1.x = (v1.x - mu) * inv * g1.x + b1.x;
  o1.y = (v1.y - mu) * inv * g1.y + b1.y;
  o1.z = (v1.z - mu) * inv * g1.z + b1.z;
  o1.w = (v1.w - mu) * inv * g1.w + b1.w;
  cr[2 * tid] = o0;
  cr[2 * tid + 1] = o1;
}

extern "C" void kernel_launch(void* const* d_in, const int* in_sizes, int n_in,
                              void* d_out, int out_size, void* d_ws, size_t ws_size,
                              hipStream_t stream) {
  const float* x  = (const float*)d_in[0];
  const float* W  = (const float*)d_in[1];
  const float* bW = (const float*)d_in[2];
  const float* g1 = (const float*)d_in[3];
  const float* b1 = (const float*)d_in[4];
  const float* g2 = (const float*)d_in[5];
  const float* b2 = (const float*)d_in[6];
  float* out = (float*)d_out;

  __hip_bfloat16* Abf = (__hip_bfloat16*)d_ws;            // 64MB
  __hip_bfloat16* Wbf = Abf + (size_t)MROWS * D;          // +8MB

  ln1_kernel<<<MROWS, 256, 0, stream>>>(x, g1, b1, Abf);
  cvt_kernel<<<(D * D / 8) / 256, 256, 0, stream>>>(W, Wbf, D * D / 8);
  dim3 grid(MROWS / BMT, D / BNT);
  gemm_kernel<<<grid, 512, 0, stream>>>(Abf, Wbf, bW, out);
  ln2_kernel<<<MROWS, 256, 0, stream>>>(out, g2, b2);
}

// Round 8
// 246.637 us; speedup vs baseline: 1.2367x; 1.0085x over previous
//
#include <hip/hip_runtime.h>
#include <hip/hip_bf16.h>
#include <math.h>

// out = LN2( gelu_erf( LN1(x) @ W^T + bW ) )
// x: [4,4096,2048] f32 -> M=16384 rows. W: [2048,2048] f32, C[m,e]=sum_d h[m,d]*W[e,d].
// GEMM R8: R4's fastest skeleton {vmcnt(counted); BAR; rd(s); stg(s+3); mma(s)} x 64 slices
// + fragment-major conflict-free LDS (proven R5-R7) + bijective XCD-chunked block swizzle.

#define D 2048
#define MROWS 16384
#define BMT 256
#define BNT 256
#define NS 64

typedef __bf16 bf16x8 __attribute__((ext_vector_type(8)));
typedef float f32x4 __attribute__((ext_vector_type(4)));

#define GLP(p) ((const __attribute__((address_space(1))) void*)(p))
#define LDSP(p) ((__attribute__((address_space(3))) void*)(p))
#define S_VMCNT(n) asm volatile("s_waitcnt vmcnt(" #n ")" ::: "memory")
#define BAR() __builtin_amdgcn_s_barrier()
#define SCHED_FENCE() __builtin_amdgcn_sched_barrier(0)

__device__ __forceinline__ float gelu_f(float v) {
  return 0.5f * v * (1.0f + erff(v * 0.70710678118654752f));
}

// ---------------- LN1: f32 row -> bf16 row ----------------
__global__ __launch_bounds__(256) void ln1_kernel(
    const float* __restrict__ x, const float* __restrict__ g,
    const float* __restrict__ b, __hip_bfloat16* __restrict__ out) {
  const int tid = threadIdx.x;
  const size_t row = blockIdx.x;
  const float4* xr = (const float4*)(x + row * D);
  float4 v0 = xr[2 * tid];
  float4 v1 = xr[2 * tid + 1];
  float s  = v0.x + v0.y + v0.z + v0.w + v1.x + v1.y + v1.z + v1.w;
  float ss = v0.x*v0.x + v0.y*v0.y + v0.z*v0.z + v0.w*v0.w
           + v1.x*v1.x + v1.y*v1.y + v1.z*v1.z + v1.w*v1.w;
#pragma unroll
  for (int off = 32; off > 0; off >>= 1) {
    s  += __shfl_down(s, off, 64);
    ss += __shfl_down(ss, off, 64);
  }
  __shared__ float red[8];
  const int w = tid >> 6;
  if ((tid & 63) == 0) { red[w] = s; red[w + 4] = ss; }
  __syncthreads();
  s  = red[0] + red[1] + red[2] + red[3];
  ss = red[4] + red[5] + red[6] + red[7];
  const float mu  = s * (1.0f / D);
  const float var = ss * (1.0f / D) - mu * mu;
  const float inv = rsqrtf(var + 1e-5f);
  const float4* gv = (const float4*)g;
  const float4* bv = (const float4*)b;
  float4 g0 = gv[2 * tid], g1 = gv[2 * tid + 1];
  float4 b0 = bv[2 * tid], b1 = bv[2 * tid + 1];
  alignas(16) __hip_bfloat16 h[8];
  h[0] = __float2bfloat16((v0.x - mu) * inv * g0.x + b0.x);
  h[1] = __float2bfloat16((v0.y - mu) * inv * g0.y + b0.y);
  h[2] = __float2bfloat16((v0.z - mu) * inv * g0.z + b0.z);
  h[3] = __float2bfloat16((v0.w - mu) * inv * g0.w + b0.w);
  h[4] = __float2bfloat16((v1.x - mu) * inv * g1.x + b1.x);
  h[5] = __float2bfloat16((v1.y - mu) * inv * g1.y + b1.y);
  h[6] = __float2bfloat16((v1.z - mu) * inv * g1.z + b1.z);
  h[7] = __float2bfloat16((v1.w - mu) * inv * g1.w + b1.w);
  *(uint4*)(out + row * D + (size_t)tid * 8) = *(const uint4*)h;
}

// ---------------- W: f32 -> bf16 ----------------
__global__ __launch_bounds__(256) void cvt_kernel(
    const float* __restrict__ W, __hip_bfloat16* __restrict__ Wb, int n8) {
  const int i = blockIdx.x * 256 + threadIdx.x;
  if (i >= n8) return;
  const float4* p = (const float4*)W + 2 * (size_t)i;
  float4 a = p[0], c = p[1];
  alignas(16) __hip_bfloat16 h[8] = {
      __float2bfloat16(a.x), __float2bfloat16(a.y),
      __float2bfloat16(a.z), __float2bfloat16(a.w),
      __float2bfloat16(c.x), __float2bfloat16(c.y),
      __float2bfloat16(c.z), __float2bfloat16(c.w)};
  *(uint4*)(Wb + (size_t)i * 8) = *(const uint4*)h;
}

// ---------------- GEMM: 256x256, 8 waves (2M x 4N), fragment-major LDS, R4 skeleton ----------------
// Slice s region (s&3)*16KB per operand: 16 frag-blocks x 1KB; byte l*16 of block fi holds
// M[fi*16 + (l&15)][s*32 + (l>>4)*8 ..+7] => every ds_read_b128 is base + lane*16 (linear).
__global__ __launch_bounds__(512, 2) void gemm_kernel(
    const __hip_bfloat16* __restrict__ A,
    const __hip_bfloat16* __restrict__ Bw,
    const float* __restrict__ bias,
    float* __restrict__ C) {
  __shared__ __hip_bfloat16 sA[4 * 8192];  // 64KB: ring of 4 slice regions
  __shared__ __hip_bfloat16 sB[4 * 8192];  // 64KB
  const int tid = threadIdx.x;
  const int l = tid & 63;
  const int wid = tid >> 6;
  const int fr = l & 15;
  const int lk = l >> 4;

  // XCD-chunked bijective swizzle: 512 blocks, xcd = bid&7 (round-robin dispatch).
  // XCD k owns m-panels bx in [8k, 8k+8), sweeping by fast -> A-panel L2-resident.
  const int nid = blockIdx.x;
  const int xk = nid & 7, j = nid >> 3;
  const int bx = (xk << 3) | (j >> 3);   // 0..63
  const int by = j & 7;                  // 0..7
  const size_t m0 = (size_t)bx * BMT;
  const int n0 = by * BNT;

  const int whm = wid >> 2;        // wave's A half (rows whm*128..+127)
  const int wn = (wid & 3) * 64;   // wave's col base in 0..255

  // staging source geometry: dest byte h*8192 + tid*16 of a region holds
  // row (h*128 + srow), cols scol..+7 of the slice.
  const int srow = ((tid >> 6) << 4) + (tid & 15);   // 0..127
  const int scol = ((tid >> 4) & 3) * 8;
  const int ldd = tid * 16;
  const __hip_bfloat16* const Ag = A + m0 * D + (size_t)srow * D + scol;
  const __hip_bfloat16* const Bg = Bw + (size_t)n0 * D + (size_t)srow * D + scol;

  auto stgA = [&](int s) {   // 2 global_load_lds
    const int ro = (s & 3) << 14;
    __builtin_amdgcn_global_load_lds(GLP(Ag + s * 32), LDSP((char*)sA + ro + ldd), 16, 0, 0);
    __builtin_amdgcn_global_load_lds(GLP(Ag + (size_t)128 * D + s * 32), LDSP((char*)sA + ro + 8192 + ldd), 16, 0, 0);
  };
  auto stgB = [&](int s) {   // 2 global_load_lds
    const int ro = (s & 3) << 14;
    __builtin_amdgcn_global_load_lds(GLP(Bg + s * 32), LDSP((char*)sB + ro + ldd), 16, 0, 0);
    __builtin_amdgcn_global_load_lds(GLP(Bg + (size_t)128 * D + s * 32), LDSP((char*)sB + ro + 8192 + ldd), 16, 0, 0);
  };

  const int abase = whm * 8192 + l * 16;           // wave's A frag base within region
  const int bbase = (wid & 3) * 4096 + l * 16;     // wave's B frag base

  bf16x8 a[8], b[4];
  f32x4 acc[8][4] = {};

  auto rdA = [&](int s) {                          // 8 linear ds_read_b128
    const char* pa = (const char*)sA + ((s & 3) << 14) + abase;
#pragma unroll
    for (int mi = 0; mi < 8; ++mi) a[mi] = *(const bf16x8*)(pa + mi * 1024);
  };
  auto rdB = [&](int s) {                          // 4 linear ds_read_b128
    const char* pb = (const char*)sB + ((s & 3) << 14) + bbase;
#pragma unroll
    for (int ni = 0; ni < 4; ++ni) b[ni] = *(const bf16x8*)(pb + ni * 1024);
  };
  auto mma32 = [&]() {
    __builtin_amdgcn_s_setprio(1);
#pragma unroll
    for (int mi = 0; mi < 8; ++mi)
#pragma unroll
      for (int ni = 0; ni < 4; ++ni)
        acc[mi][ni] = __builtin_amdgcn_mfma_f32_16x16x32_bf16(a[mi], b[ni], acc[mi][ni], 0, 0, 0);
    __builtin_amdgcn_s_setprio(0);
  };

  // prologue: stage slices 0,1,2 (12 load-insts in flight)
  stgA(0); stgB(0); stgA(1); stgB(1); stgA(2); stgB(2);

  // body(s): at top, outstanding = stg(s), stg(s+1), stg(s+2) (<=12).
  // vmcnt retires exactly stg(s); barrier makes it visible to all waves.
  for (int s = 0; s < NS; ++s) {
    if (s <= 61) { S_VMCNT(8); }
    else if (s == 62) { S_VMCNT(4); }
    else { S_VMCNT(0); }
    BAR(); SCHED_FENCE();
    rdA(s); rdB(s);
    if (s < 61) { stgA(s + 3); stgB(s + 3); }
    mma32();
  }

  // epilogue: bias + gelu, f32 stores (C/D: col=lane&15, row=(lane>>4)*4+reg)
  float bv[4];
#pragma unroll
  for (int ni = 0; ni < 4; ++ni) bv[ni] = bias[n0 + wn + ni * 16 + fr];
#pragma unroll
  for (int mi = 0; mi < 8; ++mi) {
    const size_t rbase = m0 + whm * 128 + mi * 16 + lk * 4;
#pragma unroll
    for (int rr = 0; rr < 4; ++rr) {
      float* crow = C + (rbase + rr) * D + n0 + wn + fr;
#pragma unroll
      for (int ni = 0; ni < 4; ++ni)
        crow[ni * 16] = gelu_f(acc[mi][ni][rr] + bv[ni]);
    }
  }
}

// ---------------- LN2: in-place f32 ----------------
__global__ __launch_bounds__(256) void ln2_kernel(
    float* __restrict__ C, const float* __restrict__ g, const float* __restrict__ b) {
  const int tid = threadIdx.x;
  const size_t row = blockIdx.x;
  float4* cr = (float4*)(C + row * D);
  float4 v0 = cr[2 * tid], v1 = cr[2 * tid + 1];
  float s  = v0.x + v0.y + v0.z + v0.w + v1.x + v1.y + v1.z + v1.w;
  float ss = v0.x*v0.x + v0.y*v0.y + v0.z*v0.z + v0.w*v0.w
           + v1.x*v1.x + v1.y*v1.y + v1.z*v1.z + v1.w*v1.w;
#pragma unroll
  for (int off = 32; off > 0; off >>= 1) {
    s  += __shfl_down(s, off, 64);
    ss += __shfl_down(ss, off, 64);
  }
  __shared__ float red[8];
  const int w = tid >> 6;
  if ((tid & 63) == 0) { red[w] = s; red[w + 4] = ss; }
  __syncthreads();
  s  = red[0] + red[1] + red[2] + red[3];
  ss = red[4] + red[5] + red[6] + red[7];
  const float mu  = s * (1.0f / D);
  const float var = ss * (1.0f / D) - mu * mu;
  const float inv = rsqrtf(var + 1e-5f);
  const float4* gv = (const float4*)g;
  const float4* bv = (const float4*)b;
  float4 g0 = gv[2 * tid], g1 = gv[2 * tid + 1];
  float4 b0 = bv[2 * tid], b1 = bv[2 * tid + 1];
  float4 o0, o1;
  o0.x = (v0.x - mu) * inv * g0.x + b0.x;
  o0.y = (v0.y - mu) * inv * g0.y + b0.y;
  o0.z = (v0.z - mu) * inv * g0.z + b0.z;
  o0.w = (v0.w - mu) * inv * g0.w + b0.w;
  o1.x = (v1.x - mu) * inv * g1.x + b1.x;
  o1.y = (v1.y - mu) * inv * g1.y + b1.y;
  o1.z = (v1.z - mu) * inv * g1.z + b1.z;
  o1.w = (v1.w - mu) * inv * g1.w + b1.w;
  cr[2 * tid] = o0;
  cr[2 * tid + 1] = o1;
}

extern "C" void kernel_launch(void* const* d_in, const int* in_sizes, int n_in,
                              void* d_out, int out_size, void* d_ws, size_t ws_size,
                              hipStream_t stream) {
  const float* x  = (const float*)d_in[0];
  const float* W  = (const float*)d_in[1];
  const float* bW = (const float*)d_in[2];
  const float* g1 = (const float*)d_in[3];
  const float* b1 = (const float*)d_in[4];
  const float* g2 = (const float*)d_in[5];
  const float* b2 = (const float*)d_in[6];
  float* out = (float*)d_out;

  __hip_bfloat16* Abf = (__hip_bfloat16*)d_ws;            // 64MB
  __hip_bfloat16* Wbf = Abf + (size_t)MROWS * D;          // +8MB

  ln1_kernel<<<MROWS, 256, 0, stream>>>(x, g1, b1, Abf);
  cvt_kernel<<<(D * D / 8) / 256, 256, 0, stream>>>(W, Wbf, D * D / 8);
  gemm_kernel<<<(MROWS / BMT) * (D / BNT), 512, 0, stream>>>(Abf, Wbf, bW, out);
  ln2_kernel<<<MROWS, 256, 0, stream>>>(out, g2, b2);
}